// Round 1
// baseline (4289.659 us; speedup 1.0000x reference)
//
#include <hip/hip_runtime.h>

#define N_NODES 100000
#define N_EDGES 3200000
#define C_CLUST 40
#define M_LAB   50000
#define IN_CH   128
#define HID     256
#define BN_EPS  1e-5f

// ---------------- graph preprocessing ----------------

__global__ void k_count(const int* __restrict__ dst, int* __restrict__ cnt) {
    int e = blockIdx.x * blockDim.x + threadIdx.x;
    if (e < N_EDGES) atomicAdd(&cnt[dst[e]], 1);
}

__global__ void k_dinv(const int* __restrict__ cnt, float* __restrict__ dinv) {
    int v = blockIdx.x * blockDim.x + threadIdx.x;
    if (v < N_NODES) dinv[v] = rsqrtf((float)cnt[v] + 1.0f);
}

// exclusive scan of counts -> row_ptr (3-phase)
__global__ void k_scan1(const int* __restrict__ cnt, int* __restrict__ row_ptr,
                        int* __restrict__ bsum) {
    __shared__ int s[256];
    int tid = threadIdx.x;
    int base = blockIdx.x * 1024 + tid * 4;
    int c0 = (base + 0 < N_NODES) ? cnt[base + 0] : 0;
    int c1 = (base + 1 < N_NODES) ? cnt[base + 1] : 0;
    int c2 = (base + 2 < N_NODES) ? cnt[base + 2] : 0;
    int c3 = (base + 3 < N_NODES) ? cnt[base + 3] : 0;
    int tsum = c0 + c1 + c2 + c3;
    s[tid] = tsum;
    __syncthreads();
    for (int off = 1; off < 256; off <<= 1) {
        int v = (tid >= off) ? s[tid - off] : 0;
        __syncthreads();
        s[tid] += v;
        __syncthreads();
    }
    int ex = s[tid] - tsum;
    if (base + 0 < N_NODES) row_ptr[base + 0] = ex;
    if (base + 1 < N_NODES) row_ptr[base + 1] = ex + c0;
    if (base + 2 < N_NODES) row_ptr[base + 2] = ex + c0 + c1;
    if (base + 3 < N_NODES) row_ptr[base + 3] = ex + c0 + c1 + c2;
    if (tid == 255) bsum[blockIdx.x] = s[255];
}

__global__ void k_scan2(const int* __restrict__ bsum, int* __restrict__ boff, int nb) {
    if (threadIdx.x == 0 && blockIdx.x == 0) {
        int run = 0;
        for (int i = 0; i < nb; i++) { boff[i] = run; run += bsum[i]; }
    }
}

__global__ void k_scan3(int* __restrict__ row_ptr, const int* __restrict__ boff,
                        int* __restrict__ cursor) {
    int tid = threadIdx.x;
    int base = blockIdx.x * 1024 + tid * 4;
    int off = boff[blockIdx.x];
#pragma unroll
    for (int i = 0; i < 4; i++) {
        int idx = base + i;
        if (idx < N_NODES) {
            int v = row_ptr[idx] + off;
            row_ptr[idx] = v;
            cursor[idx] = v;
        } else if (idx == N_NODES) {
            row_ptr[N_NODES] = N_EDGES;
        }
    }
}

__global__ void k_scatter(const int* __restrict__ src, const int* __restrict__ dst,
                          const float* __restrict__ dinv, int* __restrict__ cursor,
                          int* __restrict__ col, float* __restrict__ ew) {
    int e = blockIdx.x * blockDim.x + threadIdx.x;
    if (e < N_EDGES) {
        int s = src[e], d = dst[e];
        int pos = atomicAdd(&cursor[d], 1);
        col[pos] = s;
        ew[pos] = dinv[s] * dinv[d];
    }
}

// ---------------- GEMM: C[M,N] = A[M,K] @ B[K,N] ----------------
// optional: gather rows of A, BN(scale/shift)+ReLU applied to A on load,
// per-row LUT add or bias add in epilogue.
#define BM 128
#define BN 128
#define BK 16

__global__ __launch_bounds__(256) void k_gemm(
    const float* __restrict__ A, int lda,
    const float* __restrict__ B, int ldb,
    float* __restrict__ C, int ldc,
    int Mm, int Nn, int Kk,
    const int* __restrict__ gather,
    const int* __restrict__ assign,
    const float* __restrict__ lut,
    const float* __restrict__ bias,
    const float* __restrict__ scsh) {
    __shared__ float As[BK * BM];
    __shared__ float Bs[BK * BN];
    int tid = threadIdx.x;
    int tx = tid & 15, ty = tid >> 4;
    int bm = blockIdx.x * BM, bn = blockIdx.y * BN;

    float acc[8][8];
#pragma unroll
    for (int i = 0; i < 8; i++)
#pragma unroll
        for (int j = 0; j < 8; j++) acc[i][j] = 0.f;

    for (int k0 = 0; k0 < Kk; k0 += BK) {
        // stage A tile (transposed into As[k][m]), with optional BN+ReLU
#pragma unroll
        for (int L0 = 0; L0 < 2; L0++) {
            int L = tid + L0 * 256;
            int r = L >> 2, kq = L & 3;
            int row = bm + r;
            float4 av = make_float4(0.f, 0.f, 0.f, 0.f);
            if (row < Mm) {
                int arow = gather ? gather[row] : row;
                av = *(const float4*)&A[(size_t)arow * lda + k0 + kq * 4];
                if (scsh) {
                    int kc = k0 + kq * 4;
                    float4 sc = *(const float4*)&scsh[kc];
                    float4 sh = *(const float4*)&scsh[HID + kc];
                    av.x = fmaxf(fmaf(av.x, sc.x, sh.x), 0.f);
                    av.y = fmaxf(fmaf(av.y, sc.y, sh.y), 0.f);
                    av.z = fmaxf(fmaf(av.z, sc.z, sh.z), 0.f);
                    av.w = fmaxf(fmaf(av.w, sc.w, sh.w), 0.f);
                }
            }
            As[(kq * 4 + 0) * BM + r] = av.x;
            As[(kq * 4 + 1) * BM + r] = av.y;
            As[(kq * 4 + 2) * BM + r] = av.z;
            As[(kq * 4 + 3) * BM + r] = av.w;
        }
        // stage B tile
#pragma unroll
        for (int L0 = 0; L0 < 2; L0++) {
            int L = tid + L0 * 256;
            int kr = L >> 5, cq = L & 31;
            int colg = bn + cq * 4;
            float4 bv = make_float4(0.f, 0.f, 0.f, 0.f);
            if (colg < Nn) bv = *(const float4*)&B[(size_t)(k0 + kr) * ldb + colg];
            *(float4*)&Bs[kr * BN + cq * 4] = bv;
        }
        __syncthreads();
#pragma unroll
        for (int kk = 0; kk < BK; kk++) {
            float a[8], b[8];
            *(float4*)&a[0] = *(const float4*)&As[kk * BM + ty * 8];
            *(float4*)&a[4] = *(const float4*)&As[kk * BM + ty * 8 + 4];
            *(float4*)&b[0] = *(const float4*)&Bs[kk * BN + tx * 8];
            *(float4*)&b[4] = *(const float4*)&Bs[kk * BN + tx * 8 + 4];
#pragma unroll
            for (int i = 0; i < 8; i++)
#pragma unroll
                for (int j = 0; j < 8; j++) acc[i][j] = fmaf(a[i], b[j], acc[i][j]);
        }
        __syncthreads();
    }

#pragma unroll
    for (int i = 0; i < 8; i++) {
        int row = bm + ty * 8 + i;
        if (row >= Mm) continue;
        float* crow = C + (size_t)row * ldc;
        const float* lrow = lut ? (lut + (size_t)assign[row] * ldc) : nullptr;
#pragma unroll
        for (int j = 0; j < 8; j += 4) {
            int colg = bn + tx * 8 + j;
            if (colg < Nn) {
                float4 v;
                v.x = acc[i][j + 0]; v.y = acc[i][j + 1];
                v.z = acc[i][j + 2]; v.w = acc[i][j + 3];
                if (lrow) {
                    v.x += lrow[colg + 0]; v.y += lrow[colg + 1];
                    v.z += lrow[colg + 2]; v.w += lrow[colg + 3];
                } else if (bias) {
                    v.x += bias[colg + 0]; v.y += bias[colg + 1];
                    v.z += bias[colg + 2]; v.w += bias[colg + 3];
                }
                *(float4*)&crow[colg] = v;
            }
        }
    }
}

// ---------------- aggregation: out[v] = sum_e w_e*T[src_e] + dinv[v]^2*T[v] (+ b) ----
// CH = row width in floats (128 or 256). CH=128 packs 2 nodes per wave.

template <int CH>
__global__ __launch_bounds__(256) void k_agg_t(
    const float* __restrict__ T, const int* __restrict__ row_ptr,
    const int* __restrict__ col, const float* __restrict__ ew,
    const float* __restrict__ dinv, const float* __restrict__ bias,
    float* __restrict__ out) {
    constexpr int LPN = CH / 4;    // lanes per node
    constexpr int NPW = 64 / LPN;  // nodes per wave
    int wid = threadIdx.x >> 6, lane = threadIdx.x & 63;
    int v = blockIdx.x * (4 * NPW) + wid * NPW + lane / LPN;
    if (v >= N_NODES) return;
    int c4 = (lane % LPN) * 4;
    int beg = row_ptr[v], end = row_ptr[v + 1];
    float4 acc = make_float4(0.f, 0.f, 0.f, 0.f);
    int j = beg;
    for (; j + 4 <= end; j += 4) {
        int s0 = col[j], s1 = col[j + 1], s2 = col[j + 2], s3 = col[j + 3];
        float w0 = ew[j], w1 = ew[j + 1], w2 = ew[j + 2], w3 = ew[j + 3];
        float4 t0 = *(const float4*)&T[(size_t)s0 * CH + c4];
        float4 t1 = *(const float4*)&T[(size_t)s1 * CH + c4];
        float4 t2 = *(const float4*)&T[(size_t)s2 * CH + c4];
        float4 t3 = *(const float4*)&T[(size_t)s3 * CH + c4];
        acc.x = fmaf(w0, t0.x, acc.x); acc.y = fmaf(w0, t0.y, acc.y);
        acc.z = fmaf(w0, t0.z, acc.z); acc.w = fmaf(w0, t0.w, acc.w);
        acc.x = fmaf(w1, t1.x, acc.x); acc.y = fmaf(w1, t1.y, acc.y);
        acc.z = fmaf(w1, t1.z, acc.z); acc.w = fmaf(w1, t1.w, acc.w);
        acc.x = fmaf(w2, t2.x, acc.x); acc.y = fmaf(w2, t2.y, acc.y);
        acc.z = fmaf(w2, t2.z, acc.z); acc.w = fmaf(w2, t2.w, acc.w);
        acc.x = fmaf(w3, t3.x, acc.x); acc.y = fmaf(w3, t3.y, acc.y);
        acc.z = fmaf(w3, t3.z, acc.z); acc.w = fmaf(w3, t3.w, acc.w);
    }
    for (; j < end; j++) {
        int s = col[j];
        float w = ew[j];
        float4 t = *(const float4*)&T[(size_t)s * CH + c4];
        acc.x = fmaf(w, t.x, acc.x); acc.y = fmaf(w, t.y, acc.y);
        acc.z = fmaf(w, t.z, acc.z); acc.w = fmaf(w, t.w, acc.w);
    }
    float dv = dinv[v];
    float sw = dv * dv;
    float4 tv = *(const float4*)&T[(size_t)v * CH + c4];
    acc.x = fmaf(sw, tv.x, acc.x);
    acc.y = fmaf(sw, tv.y, acc.y);
    acc.z = fmaf(sw, tv.z, acc.z);
    acc.w = fmaf(sw, tv.w, acc.w);
    if (bias) {
        float4 bb = *(const float4*)&bias[c4];
        acc.x += bb.x; acc.y += bb.y; acc.z += bb.z; acc.w += bb.w;
    }
    *(float4*)&out[(size_t)v * CH + c4] = acc;
}

// ---------------- batch norm (stats + fold; apply is fused into consumers) ----------

__global__ void k_bnstats(const float* __restrict__ H, float* __restrict__ stats) {
    int c = threadIdx.x;
    float s = 0.f, q = 0.f;
    for (int r = blockIdx.x; r < N_NODES; r += gridDim.x) {
        float v = H[(size_t)r * HID + c];
        s += v;
        q += v * v;
    }
    atomicAdd(&stats[c], s);
    atomicAdd(&stats[HID + c], q);
}

__global__ void k_bnfin(const float* __restrict__ stats, const float* __restrict__ g,
                        const float* __restrict__ be, float* __restrict__ scsh) {
    int c = threadIdx.x;
    float mean = stats[c] * (1.0f / N_NODES);
    float var = stats[HID + c] * (1.0f / N_NODES) - mean * mean;
    float sc = g[c] * rsqrtf(var + BN_EPS);
    scsh[c] = sc;
    scsh[HID + c] = be[c] - mean * sc;
}

// ---------------- cluster pooling ----------------

__global__ void k_assign(const float* __restrict__ cid, int* __restrict__ assign,
                         float* __restrict__ ccount) {
    int i = blockIdx.x * blockDim.x + threadIdx.x;
    if (i < M_LAB) {
        const float* row = cid + (size_t)i * C_CLUST;
        float best = row[0];
        int bi = 0;
        for (int j = 1; j < C_CLUST; j++) {
            float v = row[j];
            if (v > best) { best = v; bi = j; }
        }
        assign[i] = bi;
        atomicAdd(&ccount[bi], 1.0f);
    }
}

__global__ __launch_bounds__(256) void k_csum(const float* __restrict__ H,
                                              const int* __restrict__ cindex,
                                              const int* __restrict__ assign,
                                              float* __restrict__ cfsum,
                                              const float* __restrict__ scsh) {
    __shared__ float lacc[C_CLUST * HID];  // 40 KB
    int tid = threadIdx.x;
    for (int k = tid; k < C_CLUST * HID; k += 256) lacc[k] = 0.f;
    __syncthreads();
    int wid = tid >> 6, lane = tid & 63;
    float4 sc4 = *(const float4*)&scsh[lane * 4];
    float4 sh4 = *(const float4*)&scsh[HID + lane * 4];
    int base = blockIdx.x * 512;
    int endr = min(base + 512, M_LAB);
    for (int r = base + wid; r < endr; r += 4) {
        int c = assign[r];
        int idx = cindex[r];
        float4 t = *(const float4*)&H[(size_t)idx * HID + lane * 4];
        t.x = fmaxf(fmaf(t.x, sc4.x, sh4.x), 0.f);
        t.y = fmaxf(fmaf(t.y, sc4.y, sh4.y), 0.f);
        t.z = fmaxf(fmaf(t.z, sc4.z, sh4.z), 0.f);
        t.w = fmaxf(fmaf(t.w, sc4.w, sh4.w), 0.f);
        float* dstp = &lacc[c * HID + lane * 4];
        atomicAdd(&dstp[0], t.x);
        atomicAdd(&dstp[1], t.y);
        atomicAdd(&dstp[2], t.z);
        atomicAdd(&dstp[3], t.w);
    }
    __syncthreads();
    for (int k = tid; k < C_CLUST * HID; k += 256) {
        float v = lacc[k];
        if (v != 0.f) atomicAdd(&cfsum[k], v);
    }
}

__global__ void k_cfin(const float* __restrict__ cfsum, const float* __restrict__ ccount,
                       float* __restrict__ cf) {
    int c = blockIdx.x, k = threadIdx.x;
    cf[c * HID + k] = cfsum[c * HID + k] / ccount[c];
}

// LUT1[c][j] = fcb[j] + sum_k cf[c][k]*fcW[(k+256)*1600+j]   (x1 contribution, first half)
// LUT2[c][j] = fcb[j] + sum_k cf[c][k]*fcW[k*1600+j]         (x1 contribution, second half)
__global__ void k_lut(const float* __restrict__ cf, const float* __restrict__ fcW,
                      const float* __restrict__ fcb, float* __restrict__ lut1,
                      float* __restrict__ lut2) {
    __shared__ float scf[HID];
    int c = blockIdx.y;
    int tid = threadIdx.x;
    scf[tid] = cf[c * HID + tid];
    __syncthreads();
    int j = blockIdx.x * 256 + tid;
    if (j < C_CLUST * C_CLUST) {
        float a1 = fcb[j], a2 = fcb[j];
        for (int k = 0; k < HID; k++) {
            float cv = scf[k];
            a2 = fmaf(cv, fcW[(size_t)k * 1600 + j], a2);
            a1 = fmaf(cv, fcW[(size_t)(k + HID) * 1600 + j], a1);
        }
        lut1[c * 1600 + j] = a1;
        lut2[c * 1600 + j] = a2;
    }
}

// ---------------- launch ----------------

extern "C" void kernel_launch(void* const* d_in, const int* in_sizes, int n_in,
                              void* d_out, int out_size, void* d_ws, size_t ws_size,
                              hipStream_t stream) {
    const float* x    = (const float*)d_in[0];
    const int*   ei   = (const int*)d_in[1];
    const float* cid  = (const float*)d_in[2];
    const int*   cidx = (const int*)d_in[3];
    const float* W0   = (const float*)d_in[4];
    const float* b0   = (const float*)d_in[5];
    const float* g0   = (const float*)d_in[6];
    const float* be0  = (const float*)d_in[7];
    const float* W1   = (const float*)d_in[8];
    const float* b1   = (const float*)d_in[9];
    const float* g1   = (const float*)d_in[10];
    const float* be1  = (const float*)d_in[11];
    const float* W2   = (const float*)d_in[12];
    const float* b2   = (const float*)d_in[13];
    const float* g2   = (const float*)d_in[14];
    const float* be2  = (const float*)d_in[15];
    const float* fcW  = (const float*)d_in[16];
    const float* fcb  = (const float*)d_in[17];
    float* out = (float*)d_out;

    char* ws = (char*)d_ws;
    size_t off = 0;
    auto alloc = [&](size_t b) -> char* {
        char* p = ws + off;
        off += (b + 255) & ~(size_t)255;
        return p;
    };
    float* H1     = (float*)alloc((size_t)N_NODES * HID * 4);   // 102.4 MB
    float* H2     = (float*)alloc((size_t)N_NODES * HID * 4);   // 102.4 MB
    int*   col    = (int*)alloc((size_t)N_EDGES * 4);
    float* ew     = (float*)alloc((size_t)N_EDGES * 4);
    int*   counts = (int*)alloc((size_t)N_NODES * 4);
    float* dinv   = (float*)alloc((size_t)N_NODES * 4);
    int*   rowptr = (int*)alloc((size_t)(N_NODES + 1) * 4);
    int*   cursor = (int*)alloc((size_t)N_NODES * 4);
    int*   bsum   = (int*)alloc(512);
    int*   boff   = (int*)alloc(512);
    float* stats  = (float*)alloc(2 * HID * 4);
    float* scsh   = (float*)alloc(2 * HID * 4);
    int*   assign = (int*)alloc((size_t)M_LAB * 4);
    float* ccount = (float*)alloc(256);
    float* cfsum  = (float*)alloc((size_t)C_CLUST * HID * 4);
    float* cf     = (float*)alloc((size_t)C_CLUST * HID * 4);
    float* lut1   = (float*)alloc((size_t)C_CLUST * 1600 * 4);
    float* lut2   = (float*)alloc((size_t)C_CLUST * 1600 * 4);
    (void)ws_size; (void)in_sizes; (void)n_in; (void)out_size;

    const int* src = ei;
    const int* dst = ei + N_EDGES;

    // graph preprocessing -> CSR
    hipMemsetAsync(counts, 0, (size_t)N_NODES * 4, stream);
    k_count<<<(N_EDGES + 255) / 256, 256, 0, stream>>>(dst, counts);
    k_dinv<<<(N_NODES + 255) / 256, 256, 0, stream>>>(counts, dinv);
    k_scan1<<<98, 256, 0, stream>>>(counts, rowptr, bsum);
    k_scan2<<<1, 64, 0, stream>>>(bsum, boff, 98);
    k_scan3<<<98, 256, 0, stream>>>(rowptr, boff, cursor);
    k_scatter<<<(N_EDGES + 255) / 256, 256, 0, stream>>>(src, dst, dinv, cursor, col, ew);

    dim3 gg((N_NODES + BM - 1) / BM, HID / BN);

    // ---- layer 0 (reordered: agg(x) @ W0 + b0; agg is linear) ----
    k_agg_t<IN_CH><<<N_NODES / 8, 256, 0, stream>>>(x, rowptr, col, ew, dinv,
                                                    nullptr, H2);
    k_gemm<<<gg, 256, 0, stream>>>(H2, IN_CH, W0, HID, H1, HID, N_NODES, HID, IN_CH,
                                   nullptr, nullptr, nullptr, b0, nullptr);
    hipMemsetAsync(stats, 0, 2 * HID * 4, stream);
    k_bnstats<<<512, 256, 0, stream>>>(H1, stats);
    k_bnfin<<<1, 256, 0, stream>>>(stats, g0, be0, scsh);

    // ---- layers 1, 2 (BN+ReLU of previous layer fused into GEMM A-load) ----
    const float* Ws[2] = {W1, W2};
    const float* bs[2] = {b1, b2};
    const float* gs[2] = {g1, g2};
    const float* bes[2] = {be1, be2};
    for (int l = 0; l < 2; l++) {
        k_gemm<<<gg, 256, 0, stream>>>(H1, HID, Ws[l], HID, H2, HID, N_NODES, HID, HID,
                                       nullptr, nullptr, nullptr, nullptr, scsh);
        k_agg_t<HID><<<N_NODES / 4, 256, 0, stream>>>(H2, rowptr, col, ew, dinv,
                                                      bs[l], H1);
        hipMemsetAsync(stats, 0, 2 * HID * 4, stream);
        k_bnstats<<<512, 256, 0, stream>>>(H1, stats);
        k_bnfin<<<1, 256, 0, stream>>>(stats, gs[l], bes[l], scsh);
    }

    // ---- cluster pooling (BN+ReLU of layer 2 fused into consumers) ----
    hipMemsetAsync(ccount, 0, 256, stream);
    hipMemsetAsync(cfsum, 0, (size_t)C_CLUST * HID * 4, stream);
    k_assign<<<(M_LAB + 255) / 256, 256, 0, stream>>>(cid, assign, ccount);
    k_csum<<<(M_LAB + 511) / 512, 256, 0, stream>>>(H1, cidx, assign, cfsum, scsh);
    k_cfin<<<C_CLUST, HID, 0, stream>>>(cfsum, ccount, cf);
    k_lut<<<dim3(7, C_CLUST), 256, 0, stream>>>(cf, fcW, fcb, lut1, lut2);

    // final FC: out[0:M]   = xs @ fcW_top + LUT1[assign]
    //           out[M:2M]  = xs @ fcW_bot + LUT2[assign]
    dim3 gf((M_LAB + BM - 1) / BM, (1600 + BN - 1) / BN);
    k_gemm<<<gf, 256, 0, stream>>>(H1, HID, fcW, 1600, out, 1600, M_LAB, 1600, HID,
                                   cidx, assign, lut1, nullptr, scsh);
    k_gemm<<<gf, 256, 0, stream>>>(H1, HID, fcW + (size_t)HID * 1600, 1600,
                                   out + (size_t)M_LAB * 1600, 1600, M_LAB, 1600, HID,
                                   cidx, assign, lut2, nullptr, scsh);
}

// Round 2
// 3613.713 us; speedup vs baseline: 1.1871x; 1.1871x over previous
//
#include <hip/hip_runtime.h>

#define N_NODES 100000
#define N_EDGES 3200000
#define C_CLUST 40
#define M_LAB   50000
#define IN_CH   128
#define HID     256
#define BN_EPS  1e-5f

typedef __attribute__((ext_vector_type(8))) short short8v;
typedef __attribute__((ext_vector_type(4))) float f32x4;

// ---------------- graph preprocessing ----------------

__global__ void k_count(const int* __restrict__ dst, int* __restrict__ cnt) {
    int e = blockIdx.x * blockDim.x + threadIdx.x;
    if (e < N_EDGES) atomicAdd(&cnt[dst[e]], 1);
}

__global__ void k_dinv(const int* __restrict__ cnt, float* __restrict__ dinv) {
    int v = blockIdx.x * blockDim.x + threadIdx.x;
    if (v < N_NODES) dinv[v] = rsqrtf((float)cnt[v] + 1.0f);
}

__global__ void k_scan1(const int* __restrict__ cnt, int* __restrict__ row_ptr,
                        int* __restrict__ bsum) {
    __shared__ int s[256];
    int tid = threadIdx.x;
    int base = blockIdx.x * 1024 + tid * 4;
    int c0 = (base + 0 < N_NODES) ? cnt[base + 0] : 0;
    int c1 = (base + 1 < N_NODES) ? cnt[base + 1] : 0;
    int c2 = (base + 2 < N_NODES) ? cnt[base + 2] : 0;
    int c3 = (base + 3 < N_NODES) ? cnt[base + 3] : 0;
    int tsum = c0 + c1 + c2 + c3;
    s[tid] = tsum;
    __syncthreads();
    for (int off = 1; off < 256; off <<= 1) {
        int v = (tid >= off) ? s[tid - off] : 0;
        __syncthreads();
        s[tid] += v;
        __syncthreads();
    }
    int ex = s[tid] - tsum;
    if (base + 0 < N_NODES) row_ptr[base + 0] = ex;
    if (base + 1 < N_NODES) row_ptr[base + 1] = ex + c0;
    if (base + 2 < N_NODES) row_ptr[base + 2] = ex + c0 + c1;
    if (base + 3 < N_NODES) row_ptr[base + 3] = ex + c0 + c1 + c2;
    if (tid == 255) bsum[blockIdx.x] = s[255];
}

__global__ void k_scan2(const int* __restrict__ bsum, int* __restrict__ boff, int nb) {
    if (threadIdx.x == 0 && blockIdx.x == 0) {
        int run = 0;
        for (int i = 0; i < nb; i++) { boff[i] = run; run += bsum[i]; }
    }
}

__global__ void k_scan3(int* __restrict__ row_ptr, const int* __restrict__ boff,
                        int* __restrict__ cursor) {
    int tid = threadIdx.x;
    int base = blockIdx.x * 1024 + tid * 4;
    int off = boff[blockIdx.x];
#pragma unroll
    for (int i = 0; i < 4; i++) {
        int idx = base + i;
        if (idx < N_NODES) {
            int v = row_ptr[idx] + off;
            row_ptr[idx] = v;
            cursor[idx] = v;
        } else if (idx == N_NODES) {
            row_ptr[N_NODES] = N_EDGES;
        }
    }
}

__global__ void k_scatter(const int* __restrict__ src, const int* __restrict__ dst,
                          const float* __restrict__ dinv, int* __restrict__ cursor,
                          int* __restrict__ col, float* __restrict__ ew) {
    int e = blockIdx.x * blockDim.x + threadIdx.x;
    if (e < N_EDGES) {
        int s = src[e], d = dst[e];
        int pos = atomicAdd(&cursor[d], 1);
        col[pos] = s;
        ew[pos] = dinv[s] * dinv[d];
    }
}

// ---------------- weight transpose + bf16 hi/lo split ----------------
// B [Kk][Nn] fp32 (row stride ldb) -> Bt_hi/Bt_lo [Nn][Kk] bf16 (truncation split:
// hi = trunc_bf16(v), lo = trunc_bf16(v - hi); residual error ~2^-16 relative)

__global__ __launch_bounds__(256) void k_wsplit(
    const float* __restrict__ B, int ldb, int Kk, int Nn,
    unsigned short* __restrict__ bh, unsigned short* __restrict__ bl) {
    __shared__ float tile[64][65];
    int kb = blockIdx.y * 64, nb = blockIdx.x * 64;
    int t = threadIdx.x;
    int lk = t >> 6, ln = t & 63;
#pragma unroll
    for (int i = 0; i < 16; i++) {
        int k = lk * 16 + i;
        int kk = kb + k, nn = nb + ln;
        tile[k][ln] = (kk < Kk && nn < Nn) ? B[(size_t)kk * ldb + nn] : 0.f;
    }
    __syncthreads();
    int wn = t >> 6, wk = t & 63;
#pragma unroll
    for (int i = 0; i < 16; i++) {
        int n = wn * 16 + i;
        int nn = nb + n, kk = kb + wk;
        if (nn < Nn && kk < Kk) {
            float v = tile[wk][n];
            unsigned u = __float_as_uint(v);
            float hf = __uint_as_float(u & 0xFFFF0000u);
            float l = v - hf;
            bh[(size_t)nn * Kk + kk] = (unsigned short)(u >> 16);
            bl[(size_t)nn * Kk + kk] = (unsigned short)(__float_as_uint(l) >> 16);
        }
    }
}

// ---------------- MFMA GEMM: C[M,N] = A[M,K] @ B[K,N] via split-bf16 3-pass --------
// A fp32 (optional gather + BN/ReLU on load); B pre-split [N][K] bf16 hi/lo.
// 128x128 tile, BK=32, 4 waves (each 64x64 = 4x4 16x16 fragments).
// LDS tiles [128 rows][32 k] bf16, 16B-granule XOR swizzle: g_phys = g ^ ((row>>1)&3).

#define GBM 128
#define GBN 128
#define GBK 32

__global__ __launch_bounds__(256, 2) void k_mgemm(
    const float* __restrict__ A, int lda,
    const unsigned short* __restrict__ Bh, const unsigned short* __restrict__ Bl,
    float* __restrict__ C, int ldc,
    int Mm, int Nn, int Kk,
    const int* __restrict__ gather,
    const int* __restrict__ assign,
    const float* __restrict__ lut,
    const float* __restrict__ bias,
    const float* __restrict__ scsh) {
    __shared__ unsigned short Ah[GBM * GBK];
    __shared__ unsigned short Al[GBM * GBK];
    __shared__ unsigned short Bhs[GBN * GBK];
    __shared__ unsigned short Bls[GBN * GBK];
    int t = threadIdx.x;
    int lane = t & 63, w = t >> 6;
    int bm = blockIdx.x * GBM, bn = blockIdx.y * GBN;
    int wr = (w >> 1) * 64, wc = (w & 1) * 64;

    f32x4 acc[4][4];
#pragma unroll
    for (int i = 0; i < 4; i++)
#pragma unroll
        for (int j = 0; j < 4; j++) acc[i][j] = (f32x4){0.f, 0.f, 0.f, 0.f};

    for (int k0 = 0; k0 < Kk; k0 += GBK) {
        // ---- stage A (128x32 fp32 -> hi/lo bf16), 4 passes of 256x float4 ----
#pragma unroll
        for (int L = 0; L < 4; L++) {
            int idx = t + L * 256;            // 0..1023
            int r = idx >> 3, kq = idx & 7;   // row, k-quad (4 floats)
            int row = bm + r;
            float4 v = make_float4(0.f, 0.f, 0.f, 0.f);
            if (row < Mm) {
                int ar = gather ? gather[row] : row;
                v = *(const float4*)&A[(size_t)ar * lda + k0 + kq * 4];
                if (scsh) {
                    int kc = k0 + kq * 4;
                    float4 sc = *(const float4*)&scsh[kc];
                    float4 sh = *(const float4*)&scsh[HID + kc];
                    v.x = fmaxf(fmaf(v.x, sc.x, sh.x), 0.f);
                    v.y = fmaxf(fmaf(v.y, sc.y, sh.y), 0.f);
                    v.z = fmaxf(fmaf(v.z, sc.z, sh.z), 0.f);
                    v.w = fmaxf(fmaf(v.w, sc.w, sh.w), 0.f);
                }
            }
            unsigned bx = __float_as_uint(v.x), by = __float_as_uint(v.y);
            unsigned bz = __float_as_uint(v.z), bw = __float_as_uint(v.w);
            float lx = v.x - __uint_as_float(bx & 0xFFFF0000u);
            float ly = v.y - __uint_as_float(by & 0xFFFF0000u);
            float lz = v.z - __uint_as_float(bz & 0xFFFF0000u);
            float lw = v.w - __uint_as_float(bw & 0xFFFF0000u);
            unsigned uh0 = (bx >> 16) | (by & 0xFFFF0000u);
            unsigned uh1 = (bz >> 16) | (bw & 0xFFFF0000u);
            unsigned ul0 = (__float_as_uint(lx) >> 16) | (__float_as_uint(ly) & 0xFFFF0000u);
            unsigned ul1 = (__float_as_uint(lz) >> 16) | (__float_as_uint(lw) & 0xFFFF0000u);
            int g = kq >> 1, hf = kq & 1;
            int gp = g ^ ((r >> 1) & 3);
            int off = r * 32 + gp * 8 + hf * 4;  // ushort units
            *(uint2*)&Ah[off] = make_uint2(uh0, uh1);
            *(uint2*)&Al[off] = make_uint2(ul0, ul1);
        }
        // ---- stage B (hi/lo, 128 cols x 32 k bf16), 2 passes of 256x 16B ----
#pragma unroll
        for (int L = 0; L < 2; L++) {
            int idx = t + L * 256;            // 0..511
            int n = idx >> 2, c = idx & 3;    // col-row, 16B granule
            int colg = bn + n;
            int gp = c ^ ((n >> 1) & 3);
            int off = n * 32 + gp * 8;
            if (colg < Nn) {
                size_t gb = (size_t)colg * Kk + k0 + c * 8;
                *(uint4*)&Bhs[off] = *(const uint4*)&Bh[gb];
                *(uint4*)&Bls[off] = *(const uint4*)&Bl[gb];
            } else {
                *(uint4*)&Bhs[off] = make_uint4(0, 0, 0, 0);
                *(uint4*)&Bls[off] = make_uint4(0, 0, 0, 0);
            }
        }
        __syncthreads();

        // ---- fragments + 3-pass MFMA ----
        int rl = lane & 15, kb = lane >> 4;
        short8v afh[4], afl[4], bfh[4], bfl[4];
#pragma unroll
        for (int i = 0; i < 4; i++) {
            int r = wr + i * 16 + rl;
            int off = r * 32 + (kb ^ ((r >> 1) & 3)) * 8;
            afh[i] = *(const short8v*)&Ah[off];
            afl[i] = *(const short8v*)&Al[off];
        }
#pragma unroll
        for (int j = 0; j < 4; j++) {
            int n = wc + j * 16 + rl;
            int off = n * 32 + (kb ^ ((n >> 1) & 3)) * 8;
            bfh[j] = *(const short8v*)&Bhs[off];
            bfl[j] = *(const short8v*)&Bls[off];
        }
#pragma unroll
        for (int i = 0; i < 4; i++)
#pragma unroll
            for (int j = 0; j < 4; j++) {
                acc[i][j] = __builtin_amdgcn_mfma_f32_16x16x32_bf16(afh[i], bfh[j], acc[i][j], 0, 0, 0);
                acc[i][j] = __builtin_amdgcn_mfma_f32_16x16x32_bf16(afh[i], bfl[j], acc[i][j], 0, 0, 0);
                acc[i][j] = __builtin_amdgcn_mfma_f32_16x16x32_bf16(afl[i], bfh[j], acc[i][j], 0, 0, 0);
            }
        __syncthreads();
    }

    // ---- epilogue: D col=lane&15, row=(lane>>4)*4+reg ----
    int rl = lane & 15, rg = lane >> 4;
#pragma unroll
    for (int i = 0; i < 4; i++) {
        int rowb = bm + wr + i * 16 + rg * 4;
#pragma unroll
        for (int rr = 0; rr < 4; rr++) {
            int r = rowb + rr;
            if (r >= Mm) continue;
            const float* lrow = lut ? (lut + (size_t)assign[r] * ldc) : nullptr;
            float* crow = C + (size_t)r * ldc;
#pragma unroll
            for (int j = 0; j < 4; j++) {
                int cg = bn + wc + j * 16 + rl;
                if (cg < Nn) {
                    float vv = acc[i][j][rr];
                    if (lrow) vv += lrow[cg];
                    else if (bias) vv += bias[cg];
                    crow[cg] = vv;
                }
            }
        }
    }
}

// ---------------- aggregation: out[v] = sum_e w_e*T[src_e] + dinv[v]^2*T[v] (+ b) ----

template <int CH>
__global__ __launch_bounds__(256) void k_agg_t(
    const float* __restrict__ T, const int* __restrict__ row_ptr,
    const int* __restrict__ col, const float* __restrict__ ew,
    const float* __restrict__ dinv, const float* __restrict__ bias,
    float* __restrict__ out) {
    constexpr int LPN = CH / 4;
    constexpr int NPW = 64 / LPN;
    int wid = threadIdx.x >> 6, lane = threadIdx.x & 63;
    int v = blockIdx.x * (4 * NPW) + wid * NPW + lane / LPN;
    if (v >= N_NODES) return;
    int c4 = (lane % LPN) * 4;
    int beg = row_ptr[v], end = row_ptr[v + 1];
    float4 acc = make_float4(0.f, 0.f, 0.f, 0.f);
    int j = beg;
    for (; j + 4 <= end; j += 4) {
        int s0 = col[j], s1 = col[j + 1], s2 = col[j + 2], s3 = col[j + 3];
        float w0 = ew[j], w1 = ew[j + 1], w2 = ew[j + 2], w3 = ew[j + 3];
        float4 t0 = *(const float4*)&T[(size_t)s0 * CH + c4];
        float4 t1 = *(const float4*)&T[(size_t)s1 * CH + c4];
        float4 t2 = *(const float4*)&T[(size_t)s2 * CH + c4];
        float4 t3 = *(const float4*)&T[(size_t)s3 * CH + c4];
        acc.x = fmaf(w0, t0.x, acc.x); acc.y = fmaf(w0, t0.y, acc.y);
        acc.z = fmaf(w0, t0.z, acc.z); acc.w = fmaf(w0, t0.w, acc.w);
        acc.x = fmaf(w1, t1.x, acc.x); acc.y = fmaf(w1, t1.y, acc.y);
        acc.z = fmaf(w1, t1.z, acc.z); acc.w = fmaf(w1, t1.w, acc.w);
        acc.x = fmaf(w2, t2.x, acc.x); acc.y = fmaf(w2, t2.y, acc.y);
        acc.z = fmaf(w2, t2.z, acc.z); acc.w = fmaf(w2, t2.w, acc.w);
        acc.x = fmaf(w3, t3.x, acc.x); acc.y = fmaf(w3, t3.y, acc.y);
        acc.z = fmaf(w3, t3.z, acc.z); acc.w = fmaf(w3, t3.w, acc.w);
    }
    for (; j < end; j++) {
        int s = col[j];
        float w = ew[j];
        float4 t = *(const float4*)&T[(size_t)s * CH + c4];
        acc.x = fmaf(w, t.x, acc.x); acc.y = fmaf(w, t.y, acc.y);
        acc.z = fmaf(w, t.z, acc.z); acc.w = fmaf(w, t.w, acc.w);
    }
    float dv = dinv[v];
    float sw = dv * dv;
    float4 tv = *(const float4*)&T[(size_t)v * CH + c4];
    acc.x = fmaf(sw, tv.x, acc.x);
    acc.y = fmaf(sw, tv.y, acc.y);
    acc.z = fmaf(sw, tv.z, acc.z);
    acc.w = fmaf(sw, tv.w, acc.w);
    if (bias) {
        float4 bb = *(const float4*)&bias[c4];
        acc.x += bb.x; acc.y += bb.y; acc.z += bb.z; acc.w += bb.w;
    }
    *(float4*)&out[(size_t)v * CH + c4] = acc;
}

// ---------------- batch norm (stats + fold; apply fused into consumers) ----------

__global__ void k_bnstats(const float* __restrict__ H, float* __restrict__ stats) {
    int c = threadIdx.x;
    float s = 0.f, q = 0.f;
    for (int r = blockIdx.x; r < N_NODES; r += gridDim.x) {
        float v = H[(size_t)r * HID + c];
        s += v;
        q += v * v;
    }
    atomicAdd(&stats[c], s);
    atomicAdd(&stats[HID + c], q);
}

__global__ void k_bnfin(const float* __restrict__ stats, const float* __restrict__ g,
                        const float* __restrict__ be, float* __restrict__ scsh) {
    int c = threadIdx.x;
    float mean = stats[c] * (1.0f / N_NODES);
    float var = stats[HID + c] * (1.0f / N_NODES) - mean * mean;
    float sc = g[c] * rsqrtf(var + BN_EPS);
    scsh[c] = sc;
    scsh[HID + c] = be[c] - mean * sc;
}

// ---------------- cluster pooling ----------------

__global__ void k_assign(const float* __restrict__ cid, int* __restrict__ assign,
                         float* __restrict__ ccount) {
    int i = blockIdx.x * blockDim.x + threadIdx.x;
    if (i < M_LAB) {
        const float* row = cid + (size_t)i * C_CLUST;
        float best = row[0];
        int bi = 0;
        for (int j = 1; j < C_CLUST; j++) {
            float v = row[j];
            if (v > best) { best = v; bi = j; }
        }
        assign[i] = bi;
        atomicAdd(&ccount[bi], 1.0f);
    }
}

__global__ __launch_bounds__(256) void k_csum(const float* __restrict__ H,
                                              const int* __restrict__ cindex,
                                              const int* __restrict__ assign,
                                              float* __restrict__ cfsum,
                                              const float* __restrict__ scsh) {
    __shared__ float lacc[C_CLUST * HID];  // 40 KB
    int tid = threadIdx.x;
    for (int k = tid; k < C_CLUST * HID; k += 256) lacc[k] = 0.f;
    __syncthreads();
    int wid = tid >> 6, lane = tid & 63;
    float4 sc4 = *(const float4*)&scsh[lane * 4];
    float4 sh4 = *(const float4*)&scsh[HID + lane * 4];
    int base = blockIdx.x * 512;
    int endr = min(base + 512, M_LAB);
    for (int r = base + wid; r < endr; r += 4) {
        int c = assign[r];
        int idx = cindex[r];
        float4 t = *(const float4*)&H[(size_t)idx * HID + lane * 4];
        t.x = fmaxf(fmaf(t.x, sc4.x, sh4.x), 0.f);
        t.y = fmaxf(fmaf(t.y, sc4.y, sh4.y), 0.f);
        t.z = fmaxf(fmaf(t.z, sc4.z, sh4.z), 0.f);
        t.w = fmaxf(fmaf(t.w, sc4.w, sh4.w), 0.f);
        float* dstp = &lacc[c * HID + lane * 4];
        atomicAdd(&dstp[0], t.x);
        atomicAdd(&dstp[1], t.y);
        atomicAdd(&dstp[2], t.z);
        atomicAdd(&dstp[3], t.w);
    }
    __syncthreads();
    for (int k = tid; k < C_CLUST * HID; k += 256) {
        float v = lacc[k];
        if (v != 0.f) atomicAdd(&cfsum[k], v);
    }
}

__global__ void k_cfin(const float* __restrict__ cfsum, const float* __restrict__ ccount,
                       float* __restrict__ cf) {
    int c = blockIdx.x, k = threadIdx.x;
    cf[c * HID + k] = cfsum[c * HID + k] / ccount[c];
}

__global__ void k_lut(const float* __restrict__ cf, const float* __restrict__ fcW,
                      const float* __restrict__ fcb, float* __restrict__ lut1,
                      float* __restrict__ lut2) {
    __shared__ float scf[HID];
    int c = blockIdx.y;
    int tid = threadIdx.x;
    scf[tid] = cf[c * HID + tid];
    __syncthreads();
    int j = blockIdx.x * 256 + tid;
    if (j < C_CLUST * C_CLUST) {
        float a1 = fcb[j], a2 = fcb[j];
        for (int k = 0; k < HID; k++) {
            float cv = scf[k];
            a2 = fmaf(cv, fcW[(size_t)k * 1600 + j], a2);
            a1 = fmaf(cv, fcW[(size_t)(k + HID) * 1600 + j], a1);
        }
        lut1[c * 1600 + j] = a1;
        lut2[c * 1600 + j] = a2;
    }
}

// ---------------- launch ----------------

extern "C" void kernel_launch(void* const* d_in, const int* in_sizes, int n_in,
                              void* d_out, int out_size, void* d_ws, size_t ws_size,
                              hipStream_t stream) {
    const float* x    = (const float*)d_in[0];
    const int*   ei   = (const int*)d_in[1];
    const float* cid  = (const float*)d_in[2];
    const int*   cidx = (const int*)d_in[3];
    const float* W0   = (const float*)d_in[4];
    const float* b0   = (const float*)d_in[5];
    const float* g0   = (const float*)d_in[6];
    const float* be0  = (const float*)d_in[7];
    const float* W1   = (const float*)d_in[8];
    const float* b1   = (const float*)d_in[9];
    const float* g1   = (const float*)d_in[10];
    const float* be1  = (const float*)d_in[11];
    const float* W2   = (const float*)d_in[12];
    const float* b2   = (const float*)d_in[13];
    const float* g2   = (const float*)d_in[14];
    const float* be2  = (const float*)d_in[15];
    const float* fcW  = (const float*)d_in[16];
    const float* fcb  = (const float*)d_in[17];
    float* out = (float*)d_out;

    char* ws = (char*)d_ws;
    size_t off = 0;
    auto alloc = [&](size_t b) -> char* {
        char* p = ws + off;
        off += (b + 255) & ~(size_t)255;
        return p;
    };
    float* H1     = (float*)alloc((size_t)N_NODES * HID * 4);
    float* H2     = (float*)alloc((size_t)N_NODES * HID * 4);
    int*   col    = (int*)alloc((size_t)N_EDGES * 4);
    float* ew     = (float*)alloc((size_t)N_EDGES * 4);
    int*   counts = (int*)alloc((size_t)N_NODES * 4);
    float* dinv   = (float*)alloc((size_t)N_NODES * 4);
    int*   rowptr = (int*)alloc((size_t)(N_NODES + 1) * 4);
    int*   cursor = (int*)alloc((size_t)N_NODES * 4);
    int*   bsum   = (int*)alloc(512);
    int*   boff   = (int*)alloc(512);
    float* stats  = (float*)alloc(2 * HID * 4);
    float* scsh   = (float*)alloc(2 * HID * 4);
    int*   assign = (int*)alloc((size_t)M_LAB * 4);
    float* ccount = (float*)alloc(256);
    float* cfsum  = (float*)alloc((size_t)C_CLUST * HID * 4);
    float* cf     = (float*)alloc((size_t)C_CLUST * HID * 4);
    float* lut1   = (float*)alloc((size_t)C_CLUST * 1600 * 4);
    float* lut2   = (float*)alloc((size_t)C_CLUST * 1600 * 4);
    unsigned short* W0h = (unsigned short*)alloc((size_t)HID * IN_CH * 2);
    unsigned short* W0l = (unsigned short*)alloc((size_t)HID * IN_CH * 2);
    unsigned short* W1h = (unsigned short*)alloc((size_t)HID * HID * 2);
    unsigned short* W1l = (unsigned short*)alloc((size_t)HID * HID * 2);
    unsigned short* W2h = (unsigned short*)alloc((size_t)HID * HID * 2);
    unsigned short* W2l = (unsigned short*)alloc((size_t)HID * HID * 2);
    unsigned short* Fth = (unsigned short*)alloc((size_t)1600 * HID * 2);
    unsigned short* Ftl = (unsigned short*)alloc((size_t)1600 * HID * 2);
    unsigned short* Fbh = (unsigned short*)alloc((size_t)1600 * HID * 2);
    unsigned short* Fbl = (unsigned short*)alloc((size_t)1600 * HID * 2);
    (void)ws_size; (void)in_sizes; (void)n_in; (void)out_size;

    const int* src = ei;
    const int* dst = ei + N_EDGES;

    // weight transpose + split (independent of graph work)
    k_wsplit<<<dim3(4, 2), 256, 0, stream>>>(W0, HID, IN_CH, HID, W0h, W0l);
    k_wsplit<<<dim3(4, 4), 256, 0, stream>>>(W1, HID, HID, HID, W1h, W1l);
    k_wsplit<<<dim3(4, 4), 256, 0, stream>>>(W2, HID, HID, HID, W2h, W2l);
    k_wsplit<<<dim3(25, 4), 256, 0, stream>>>(fcW, 1600, HID, 1600, Fth, Ftl);
    k_wsplit<<<dim3(25, 4), 256, 0, stream>>>(fcW + (size_t)HID * 1600, 1600, HID, 1600, Fbh, Fbl);

    // graph preprocessing -> CSR
    hipMemsetAsync(counts, 0, (size_t)N_NODES * 4, stream);
    k_count<<<(N_EDGES + 255) / 256, 256, 0, stream>>>(dst, counts);
    k_dinv<<<(N_NODES + 255) / 256, 256, 0, stream>>>(counts, dinv);
    k_scan1<<<98, 256, 0, stream>>>(counts, rowptr, bsum);
    k_scan2<<<1, 64, 0, stream>>>(bsum, boff, 98);
    k_scan3<<<98, 256, 0, stream>>>(rowptr, boff, cursor);
    k_scatter<<<(N_EDGES + 255) / 256, 256, 0, stream>>>(src, dst, dinv, cursor, col, ew);

    dim3 gg((N_NODES + GBM - 1) / GBM, HID / GBN);

    // ---- layer 0 (reordered: agg(x) @ W0 + b0) ----
    k_agg_t<IN_CH><<<N_NODES / 8, 256, 0, stream>>>(x, rowptr, col, ew, dinv,
                                                    nullptr, H2);
    k_mgemm<<<gg, 256, 0, stream>>>(H2, IN_CH, W0h, W0l, H1, HID, N_NODES, HID, IN_CH,
                                    nullptr, nullptr, nullptr, b0, nullptr);
    hipMemsetAsync(stats, 0, 2 * HID * 4, stream);
    k_bnstats<<<512, 256, 0, stream>>>(H1, stats);
    k_bnfin<<<1, 256, 0, stream>>>(stats, g0, be0, scsh);

    // ---- layers 1, 2 (BN+ReLU fused into GEMM A-load) ----
    const unsigned short* Whs[2] = {W1h, W2h};
    const unsigned short* Wls[2] = {W1l, W2l};
    const float* bs[2] = {b1, b2};
    const float* gs[2] = {g1, g2};
    const float* bes[2] = {be1, be2};
    for (int l = 0; l < 2; l++) {
        k_mgemm<<<gg, 256, 0, stream>>>(H1, HID, Whs[l], Wls[l], H2, HID,
                                        N_NODES, HID, HID,
                                        nullptr, nullptr, nullptr, nullptr, scsh);
        k_agg_t<HID><<<N_NODES / 4, 256, 0, stream>>>(H2, rowptr, col, ew, dinv,
                                                      bs[l], H1);
        hipMemsetAsync(stats, 0, 2 * HID * 4, stream);
        k_bnstats<<<512, 256, 0, stream>>>(H1, stats);
        k_bnfin<<<1, 256, 0, stream>>>(stats, gs[l], bes[l], scsh);
    }

    // ---- cluster pooling (BN+ReLU of layer 2 fused into consumers) ----
    hipMemsetAsync(ccount, 0, 256, stream);
    hipMemsetAsync(cfsum, 0, (size_t)C_CLUST * HID * 4, stream);
    k_assign<<<(M_LAB + 255) / 256, 256, 0, stream>>>(cid, assign, ccount);
    k_csum<<<(M_LAB + 511) / 512, 256, 0, stream>>>(H1, cidx, assign, cfsum, scsh);
    k_cfin<<<C_CLUST, HID, 0, stream>>>(cfsum, ccount, cf);
    k_lut<<<dim3(7, C_CLUST), 256, 0, stream>>>(cf, fcW, fcb, lut1, lut2);

    // ---- final FC ----
    dim3 gf((M_LAB + GBM - 1) / GBM, (1600 + GBN - 1) / GBN);
    k_mgemm<<<gf, 256, 0, stream>>>(H1, HID, Fth, Ftl, out, 1600, M_LAB, 1600, HID,
                                    cidx, assign, lut1, nullptr, scsh);
    k_mgemm<<<gf, 256, 0, stream>>>(H1, HID, Fbh, Fbl, out + (size_t)M_LAB * 1600, 1600,
                                    M_LAB, 1600, HID, cidx, assign, lut2, nullptr, scsh);
}

// Round 3
// 2852.686 us; speedup vs baseline: 1.5037x; 1.2668x over previous
//
#include <hip/hip_runtime.h>

#define N_NODES 100000
#define N_EDGES 3200000
#define C_CLUST 40
#define M_LAB   50000
#define IN_CH   128
#define HID     256
#define BN_EPS  1e-5f

typedef __attribute__((ext_vector_type(8))) short short8v;
typedef __attribute__((ext_vector_type(4))) float f32x4;

__device__ __forceinline__ unsigned bf16r(float f) {
    unsigned u = __float_as_uint(f);
    return (u + 0x7FFFu + ((u >> 16) & 1u)) >> 16;
}
__device__ __forceinline__ unsigned pack2bf(float lo, float hi) {
    return bf16r(lo) | (bf16r(hi) << 16);
}
__device__ __forceinline__ void acc8(float* acc, uint4 u, float w) {
    acc[0] = fmaf(w, __uint_as_float(u.x << 16), acc[0]);
    acc[1] = fmaf(w, __uint_as_float(u.x & 0xFFFF0000u), acc[1]);
    acc[2] = fmaf(w, __uint_as_float(u.y << 16), acc[2]);
    acc[3] = fmaf(w, __uint_as_float(u.y & 0xFFFF0000u), acc[3]);
    acc[4] = fmaf(w, __uint_as_float(u.z << 16), acc[4]);
    acc[5] = fmaf(w, __uint_as_float(u.z & 0xFFFF0000u), acc[5]);
    acc[6] = fmaf(w, __uint_as_float(u.w << 16), acc[6]);
    acc[7] = fmaf(w, __uint_as_float(u.w & 0xFFFF0000u), acc[7]);
}

// ---------------- graph preprocessing ----------------

__global__ void k_count(const int* __restrict__ dst, int* __restrict__ cnt) {
    int e = blockIdx.x * blockDim.x + threadIdx.x;
    if (e < N_EDGES) atomicAdd(&cnt[dst[e]], 1);
}

__global__ void k_dinv(const int* __restrict__ cnt, float* __restrict__ dinv) {
    int v = blockIdx.x * blockDim.x + threadIdx.x;
    if (v < N_NODES) dinv[v] = rsqrtf((float)cnt[v] + 1.0f);
}

__global__ void k_scan1(const int* __restrict__ cnt, int* __restrict__ row_ptr,
                        int* __restrict__ bsum) {
    __shared__ int s[256];
    int tid = threadIdx.x;
    int base = blockIdx.x * 1024 + tid * 4;
    int c0 = (base + 0 < N_NODES) ? cnt[base + 0] : 0;
    int c1 = (base + 1 < N_NODES) ? cnt[base + 1] : 0;
    int c2 = (base + 2 < N_NODES) ? cnt[base + 2] : 0;
    int c3 = (base + 3 < N_NODES) ? cnt[base + 3] : 0;
    int tsum = c0 + c1 + c2 + c3;
    s[tid] = tsum;
    __syncthreads();
    for (int off = 1; off < 256; off <<= 1) {
        int v = (tid >= off) ? s[tid - off] : 0;
        __syncthreads();
        s[tid] += v;
        __syncthreads();
    }
    int ex = s[tid] - tsum;
    if (base + 0 < N_NODES) row_ptr[base + 0] = ex;
    if (base + 1 < N_NODES) row_ptr[base + 1] = ex + c0;
    if (base + 2 < N_NODES) row_ptr[base + 2] = ex + c0 + c1;
    if (base + 3 < N_NODES) row_ptr[base + 3] = ex + c0 + c1 + c2;
    if (tid == 255) bsum[blockIdx.x] = s[255];
}

__global__ void k_scan2(const int* __restrict__ bsum, int* __restrict__ boff, int nb) {
    if (threadIdx.x == 0 && blockIdx.x == 0) {
        int run = 0;
        for (int i = 0; i < nb; i++) { boff[i] = run; run += bsum[i]; }
    }
}

__global__ void k_scan3(int* __restrict__ row_ptr, const int* __restrict__ boff,
                        int* __restrict__ cursor) {
    int tid = threadIdx.x;
    int base = blockIdx.x * 1024 + tid * 4;
    int off = boff[blockIdx.x];
#pragma unroll
    for (int i = 0; i < 4; i++) {
        int idx = base + i;
        if (idx < N_NODES) {
            int v = row_ptr[idx] + off;
            row_ptr[idx] = v;
            cursor[idx] = v;
        } else if (idx == N_NODES) {
            row_ptr[N_NODES] = N_EDGES;
        }
    }
}

__global__ void k_scatter(const int* __restrict__ src, const int* __restrict__ dst,
                          const float* __restrict__ dinv, int* __restrict__ cursor,
                          int* __restrict__ col, float* __restrict__ ew) {
    int e = blockIdx.x * blockDim.x + threadIdx.x;
    if (e < N_EDGES) {
        int s = src[e], d = dst[e];
        int pos = atomicAdd(&cursor[d], 1);
        col[pos] = s;
        ew[pos] = dinv[s] * dinv[d];
    }
}

// ---------------- fp32 -> bf16 convert (for x) ----------------

__global__ void k_tobf16(const float* __restrict__ in, unsigned short* __restrict__ outb,
                         int n8) {
    int i = blockIdx.x * blockDim.x + threadIdx.x;
    if (i < n8) {
        float4 a = *(const float4*)&in[(size_t)i * 8];
        float4 b = *(const float4*)&in[(size_t)i * 8 + 4];
        uint4 r;
        r.x = pack2bf(a.x, a.y);
        r.y = pack2bf(a.z, a.w);
        r.z = pack2bf(b.x, b.y);
        r.w = pack2bf(b.z, b.w);
        *(uint4*)&outb[(size_t)i * 8] = r;
    }
}

// ---------------- weight transpose + bf16 hi/lo split ----------------

__global__ __launch_bounds__(256) void k_wsplit(
    const float* __restrict__ B, int ldb, int Kk, int Nn,
    unsigned short* __restrict__ bh, unsigned short* __restrict__ bl) {
    __shared__ float tile[64][65];
    int kb = blockIdx.y * 64, nb = blockIdx.x * 64;
    int t = threadIdx.x;
    int lk = t >> 6, ln = t & 63;
#pragma unroll
    for (int i = 0; i < 16; i++) {
        int k = lk * 16 + i;
        int kk = kb + k, nn = nb + ln;
        tile[k][ln] = (kk < Kk && nn < Nn) ? B[(size_t)kk * ldb + nn] : 0.f;
    }
    __syncthreads();
    int wn = t >> 6, wk = t & 63;
#pragma unroll
    for (int i = 0; i < 16; i++) {
        int n = wn * 16 + i;
        int nn = nb + n, kk = kb + wk;
        if (nn < Nn && kk < Kk) {
            float v = tile[wk][n];
            unsigned u = __float_as_uint(v);
            float hf = __uint_as_float(u & 0xFFFF0000u);
            float l = v - hf;
            bh[(size_t)nn * Kk + kk] = (unsigned short)(u >> 16);
            bl[(size_t)nn * Kk + kk] = (unsigned short)(__float_as_uint(l) >> 16);
        }
    }
}

// ---------------- MFMA GEMM, double-buffered single-barrier pipeline ----------------
// C[M,N] = A[M,K] @ B[K,N]; A fp32 (opt gather + BN/ReLU), B pre-split [N][K] bf16 hi/lo.
// 128x128 tile, BK=32, 4 waves; split-bf16 3-pass (hi*hi + hi*lo + lo*hi).
// Output fp32 (C, + lut/bias) or bf16 (Cb).

#define GBM 128
#define GBN 128
#define GBK 32

__global__ __launch_bounds__(256, 2) void k_mgemm(
    const float* __restrict__ A, int lda,
    const unsigned short* __restrict__ Bh, const unsigned short* __restrict__ Bl,
    float* __restrict__ C, unsigned short* __restrict__ Cb, int ldc,
    int Mm, int Nn, int Kk,
    const int* __restrict__ gather,
    const int* __restrict__ assign,
    const float* __restrict__ lut,
    const float* __restrict__ bias,
    const float* __restrict__ scsh) {
    __shared__ unsigned short Ah[2][GBM * GBK];
    __shared__ unsigned short Al[2][GBM * GBK];
    __shared__ unsigned short Bhs[2][GBN * GBK];
    __shared__ unsigned short Bls[2][GBN * GBK];
    __shared__ float sscsh[2 * HID];
    int t = threadIdx.x;
    int lane = t & 63, w = t >> 6;
    int bm = blockIdx.x * GBM, bn = blockIdx.y * GBN;
    int wr = (w >> 1) * 64, wc = (w & 1) * 64;

    if (scsh && t < 128) {
        *(float4*)&sscsh[t * 4] = *(const float4*)&scsh[t * 4];
    }

    // staging geometry (loop-invariant)
    const float* aptr[4];
    bool aval[4];
    int asw[4];
    float4 areg[4];
#pragma unroll
    for (int L = 0; L < 4; L++) {
        int idx = t + L * 256;
        int r = idx >> 3, kq = idx & 7;
        int row = bm + r;
        aval[L] = row < Mm;
        int ar = aval[L] ? (gather ? gather[row] : row) : 0;
        aptr[L] = A + (size_t)ar * lda + kq * 4;
        int gp = (kq >> 1) ^ ((r >> 1) & 3);
        asw[L] = r * 32 + gp * 8 + (kq & 1) * 4;
    }
    const unsigned short *bhptr[2], *blptr[2];
    bool bval[2];
    int bsw[2];
    uint4 bhreg[2], blreg[2];
#pragma unroll
    for (int L = 0; L < 2; L++) {
        int idx = t + L * 256;
        int n = idx >> 2, c = idx & 3;
        int colg = bn + n;
        bval[L] = colg < Nn;
        size_t base = (size_t)(bval[L] ? colg : 0) * Kk + c * 8;
        bhptr[L] = Bh + base;
        blptr[L] = Bl + base;
        int gp = c ^ ((n >> 1) & 3);
        bsw[L] = n * 32 + gp * 8;
    }
    int rl = lane & 15, kb = lane >> 4;
    int afoff[4], bfoff[4];
#pragma unroll
    for (int i = 0; i < 4; i++) {
        int r = wr + i * 16 + rl;
        afoff[i] = r * 32 + (kb ^ ((r >> 1) & 3)) * 8;
        int n = wc + i * 16 + rl;
        bfoff[i] = n * 32 + (kb ^ ((n >> 1) & 3)) * 8;
    }

    f32x4 acc[4][4];
#pragma unroll
    for (int i = 0; i < 4; i++)
#pragma unroll
        for (int j = 0; j < 4; j++) acc[i][j] = (f32x4){0.f, 0.f, 0.f, 0.f};

    auto prefetch = [&](int tile) {
        int koff = tile * GBK;
#pragma unroll
        for (int L = 0; L < 4; L++)
            areg[L] = aval[L] ? *(const float4*)(aptr[L] + koff)
                              : make_float4(0.f, 0.f, 0.f, 0.f);
#pragma unroll
        for (int L = 0; L < 2; L++) {
            if (bval[L]) {
                bhreg[L] = *(const uint4*)(bhptr[L] + koff);
                blreg[L] = *(const uint4*)(blptr[L] + koff);
            } else {
                bhreg[L] = make_uint4(0, 0, 0, 0);
                blreg[L] = make_uint4(0, 0, 0, 0);
            }
        }
    };

    auto stage = [&](int buf, int tile) {
#pragma unroll
        for (int L = 0; L < 4; L++) {
            float4 v = areg[L];
            if (scsh) {
                int kc = tile * GBK + ((t + L * 256) & 7) * 4;
                float4 sc = *(const float4*)&sscsh[kc];
                float4 sh = *(const float4*)&sscsh[HID + kc];
                v.x = fmaxf(fmaf(v.x, sc.x, sh.x), 0.f);
                v.y = fmaxf(fmaf(v.y, sc.y, sh.y), 0.f);
                v.z = fmaxf(fmaf(v.z, sc.z, sh.z), 0.f);
                v.w = fmaxf(fmaf(v.w, sc.w, sh.w), 0.f);
            }
            unsigned bx = __float_as_uint(v.x), by = __float_as_uint(v.y);
            unsigned bz = __float_as_uint(v.z), bw = __float_as_uint(v.w);
            float lx = v.x - __uint_as_float(bx & 0xFFFF0000u);
            float ly = v.y - __uint_as_float(by & 0xFFFF0000u);
            float lz = v.z - __uint_as_float(bz & 0xFFFF0000u);
            float lw = v.w - __uint_as_float(bw & 0xFFFF0000u);
            unsigned uh0 = (bx >> 16) | (by & 0xFFFF0000u);
            unsigned uh1 = (bz >> 16) | (bw & 0xFFFF0000u);
            unsigned ul0 = (__float_as_uint(lx) >> 16) | (__float_as_uint(ly) & 0xFFFF0000u);
            unsigned ul1 = (__float_as_uint(lz) >> 16) | (__float_as_uint(lw) & 0xFFFF0000u);
            *(uint2*)&Ah[buf][asw[L]] = make_uint2(uh0, uh1);
            *(uint2*)&Al[buf][asw[L]] = make_uint2(ul0, ul1);
        }
#pragma unroll
        for (int L = 0; L < 2; L++) {
            *(uint4*)&Bhs[buf][bsw[L]] = bhreg[L];
            *(uint4*)&Bls[buf][bsw[L]] = blreg[L];
        }
    };

    int nt = Kk / GBK;
    prefetch(0);
    if (scsh) __syncthreads();  // sscsh visible before first stage-use

    for (int tt = 0; tt < nt; ++tt) {
        int buf = tt & 1;
        stage(buf, tt);
        __syncthreads();
        if (tt + 1 < nt) prefetch(tt + 1);

        short8v afh[4], afl[4], bfh[4], bfl[4];
#pragma unroll
        for (int i = 0; i < 4; i++) {
            afh[i] = *(const short8v*)&Ah[buf][afoff[i]];
            afl[i] = *(const short8v*)&Al[buf][afoff[i]];
        }
#pragma unroll
        for (int j = 0; j < 4; j++) {
            bfh[j] = *(const short8v*)&Bhs[buf][bfoff[j]];
            bfl[j] = *(const short8v*)&Bls[buf][bfoff[j]];
        }
#pragma unroll
        for (int i = 0; i < 4; i++)
#pragma unroll
            for (int j = 0; j < 4; j++) {
                acc[i][j] = __builtin_amdgcn_mfma_f32_16x16x32_bf16(afh[i], bfh[j], acc[i][j], 0, 0, 0);
                acc[i][j] = __builtin_amdgcn_mfma_f32_16x16x32_bf16(afh[i], bfl[j], acc[i][j], 0, 0, 0);
                acc[i][j] = __builtin_amdgcn_mfma_f32_16x16x32_bf16(afl[i], bfh[j], acc[i][j], 0, 0, 0);
            }
    }

    // epilogue: D col=lane&15, row=(lane>>4)*4+reg
    int rg = lane >> 4;
#pragma unroll
    for (int i = 0; i < 4; i++) {
        int rowb = bm + wr + i * 16 + rg * 4;
#pragma unroll
        for (int rr = 0; rr < 4; rr++) {
            int r = rowb + rr;
            if (r >= Mm) continue;
            if (Cb) {
                unsigned short* crow = Cb + (size_t)r * ldc;
#pragma unroll
                for (int j = 0; j < 4; j++) {
                    int cg = bn + wc + j * 16 + rl;
                    if (cg < Nn) crow[cg] = (unsigned short)bf16r(acc[i][j][rr]);
                }
            } else {
                const float* lrow = lut ? (lut + (size_t)assign[r] * ldc) : nullptr;
                float* crow = C + (size_t)r * ldc;
#pragma unroll
                for (int j = 0; j < 4; j++) {
                    int cg = bn + wc + j * 16 + rl;
                    if (cg < Nn) {
                        float vv = acc[i][j][rr];
                        if (lrow) vv += lrow[cg];
                        else if (bias) vv += bias[cg];
                        crow[cg] = vv;
                    }
                }
            }
        }
    }
}

// ---------------- aggregation over bf16 rows: out fp32 ----------------

template <int CH>
__global__ __launch_bounds__(256) void k_aggb(
    const unsigned short* __restrict__ Tb, const int* __restrict__ row_ptr,
    const int* __restrict__ col, const float* __restrict__ ew,
    const float* __restrict__ dinv, const float* __restrict__ bias,
    float* __restrict__ out) {
    constexpr int LPN = CH / 8;    // lanes per node (16B bf16 per lane)
    constexpr int NPW = 64 / LPN;  // nodes per wave
    int wid = threadIdx.x >> 6, lane = threadIdx.x & 63;
    int v = blockIdx.x * (4 * NPW) + wid * NPW + lane / LPN;
    if (v >= N_NODES) return;
    int c8 = (lane % LPN) * 8;
    int beg = row_ptr[v], end = row_ptr[v + 1];
    float acc[8] = {0.f, 0.f, 0.f, 0.f, 0.f, 0.f, 0.f, 0.f};
    int j = beg;
    for (; j + 4 <= end; j += 4) {
        int s0 = col[j], s1 = col[j + 1], s2 = col[j + 2], s3 = col[j + 3];
        float w0 = ew[j], w1 = ew[j + 1], w2 = ew[j + 2], w3 = ew[j + 3];
        uint4 u0 = *(const uint4*)&Tb[(size_t)s0 * CH + c8];
        uint4 u1 = *(const uint4*)&Tb[(size_t)s1 * CH + c8];
        uint4 u2 = *(const uint4*)&Tb[(size_t)s2 * CH + c8];
        uint4 u3 = *(const uint4*)&Tb[(size_t)s3 * CH + c8];
        acc8(acc, u0, w0);
        acc8(acc, u1, w1);
        acc8(acc, u2, w2);
        acc8(acc, u3, w3);
    }
    for (; j < end; j++) {
        int s = col[j];
        float w = ew[j];
        uint4 u = *(const uint4*)&Tb[(size_t)s * CH + c8];
        acc8(acc, u, w);
    }
    float dv = dinv[v];
    float sw = dv * dv;
    uint4 uv = *(const uint4*)&Tb[(size_t)v * CH + c8];
    acc8(acc, uv, sw);
    if (bias) {
        float4 b0 = *(const float4*)&bias[c8];
        float4 b1 = *(const float4*)&bias[c8 + 4];
        acc[0] += b0.x; acc[1] += b0.y; acc[2] += b0.z; acc[3] += b0.w;
        acc[4] += b1.x; acc[5] += b1.y; acc[6] += b1.z; acc[7] += b1.w;
    }
    float4 o0 = make_float4(acc[0], acc[1], acc[2], acc[3]);
    float4 o1 = make_float4(acc[4], acc[5], acc[6], acc[7]);
    *(float4*)&out[(size_t)v * CH + c8] = o0;
    *(float4*)&out[(size_t)v * CH + c8 + 4] = o1;
}

// ---------------- batch norm (stats + fold; apply fused into consumers) ----------

__global__ void k_bnstats(const float* __restrict__ H, float* __restrict__ stats) {
    int c = threadIdx.x;
    float s = 0.f, q = 0.f;
    for (int r = blockIdx.x; r < N_NODES; r += gridDim.x) {
        float v = H[(size_t)r * HID + c];
        s += v;
        q += v * v;
    }
    atomicAdd(&stats[c], s);
    atomicAdd(&stats[HID + c], q);
}

__global__ void k_bnfin(const float* __restrict__ stats, const float* __restrict__ g,
                        const float* __restrict__ be, float* __restrict__ scsh) {
    int c = threadIdx.x;
    float mean = stats[c] * (1.0f / N_NODES);
    float var = stats[HID + c] * (1.0f / N_NODES) - mean * mean;
    float sc = g[c] * rsqrtf(var + BN_EPS);
    scsh[c] = sc;
    scsh[HID + c] = be[c] - mean * sc;
}

// ---------------- cluster pooling ----------------

__global__ void k_assign(const float* __restrict__ cid, int* __restrict__ assign,
                         float* __restrict__ ccount) {
    int i = blockIdx.x * blockDim.x + threadIdx.x;
    if (i < M_LAB) {
        const float* row = cid + (size_t)i * C_CLUST;
        float best = row[0];
        int bi = 0;
        for (int j = 1; j < C_CLUST; j++) {
            float v = row[j];
            if (v > best) { best = v; bi = j; }
        }
        assign[i] = bi;
        atomicAdd(&ccount[bi], 1.0f);
    }
}

__global__ __launch_bounds__(256) void k_csum(const float* __restrict__ H,
                                              const int* __restrict__ cindex,
                                              const int* __restrict__ assign,
                                              float* __restrict__ cfsum,
                                              const float* __restrict__ scsh) {
    __shared__ float lacc[C_CLUST * HID];  // 40 KB
    int tid = threadIdx.x;
    for (int k = tid; k < C_CLUST * HID; k += 256) lacc[k] = 0.f;
    __syncthreads();
    int wid = tid >> 6, lane = tid & 63;
    float4 sc4 = *(const float4*)&scsh[lane * 4];
    float4 sh4 = *(const float4*)&scsh[HID + lane * 4];
    int base = blockIdx.x * 512;
    int endr = min(base + 512, M_LAB);
    for (int r = base + wid; r < endr; r += 4) {
        int c = assign[r];
        int idx = cindex[r];
        float4 t = *(const float4*)&H[(size_t)idx * HID + lane * 4];
        t.x = fmaxf(fmaf(t.x, sc4.x, sh4.x), 0.f);
        t.y = fmaxf(fmaf(t.y, sc4.y, sh4.y), 0.f);
        t.z = fmaxf(fmaf(t.z, sc4.z, sh4.z), 0.f);
        t.w = fmaxf(fmaf(t.w, sc4.w, sh4.w), 0.f);
        float* dstp = &lacc[c * HID + lane * 4];
        atomicAdd(&dstp[0], t.x);
        atomicAdd(&dstp[1], t.y);
        atomicAdd(&dstp[2], t.z);
        atomicAdd(&dstp[3], t.w);
    }
    __syncthreads();
    for (int k = tid; k < C_CLUST * HID; k += 256) {
        float v = lacc[k];
        if (v != 0.f) atomicAdd(&cfsum[k], v);
    }
}

__global__ void k_cfin(const float* __restrict__ cfsum, const float* __restrict__ ccount,
                       float* __restrict__ cf) {
    int c = blockIdx.x, k = threadIdx.x;
    cf[c * HID + k] = cfsum[c * HID + k] / ccount[c];
}

__global__ void k_lut(const float* __restrict__ cf, const float* __restrict__ fcW,
                      const float* __restrict__ fcb, float* __restrict__ lut1,
                      float* __restrict__ lut2) {
    __shared__ float scf[HID];
    int c = blockIdx.y;
    int tid = threadIdx.x;
    scf[tid] = cf[c * HID + tid];
    __syncthreads();
    int j = blockIdx.x * 256 + tid;
    if (j < C_CLUST * C_CLUST) {
        float a1 = fcb[j], a2 = fcb[j];
        for (int k = 0; k < HID; k++) {
            float cv = scf[k];
            a2 = fmaf(cv, fcW[(size_t)k * 1600 + j], a2);
            a1 = fmaf(cv, fcW[(size_t)(k + HID) * 1600 + j], a1);
        }
        lut1[c * 1600 + j] = a1;
        lut2[c * 1600 + j] = a2;
    }
}

// ---------------- launch ----------------

extern "C" void kernel_launch(void* const* d_in, const int* in_sizes, int n_in,
                              void* d_out, int out_size, void* d_ws, size_t ws_size,
                              hipStream_t stream) {
    const float* x    = (const float*)d_in[0];
    const int*   ei   = (const int*)d_in[1];
    const float* cid  = (const float*)d_in[2];
    const int*   cidx = (const int*)d_in[3];
    const float* W0   = (const float*)d_in[4];
    const float* b0   = (const float*)d_in[5];
    const float* g0   = (const float*)d_in[6];
    const float* be0  = (const float*)d_in[7];
    const float* W1   = (const float*)d_in[8];
    const float* b1   = (const float*)d_in[9];
    const float* g1   = (const float*)d_in[10];
    const float* be1  = (const float*)d_in[11];
    const float* W2   = (const float*)d_in[12];
    const float* b2   = (const float*)d_in[13];
    const float* g2   = (const float*)d_in[14];
    const float* be2  = (const float*)d_in[15];
    const float* fcW  = (const float*)d_in[16];
    const float* fcb  = (const float*)d_in[17];
    float* out = (float*)d_out;

    char* ws = (char*)d_ws;
    size_t off = 0;
    auto alloc = [&](size_t b) -> char* {
        char* p = ws + off;
        off += (b + 255) & ~(size_t)255;
        return p;
    };
    float* H1     = (float*)alloc((size_t)N_NODES * HID * 4);
    float* H2     = (float*)alloc((size_t)N_NODES * HID * 4);
    int*   col    = (int*)alloc((size_t)N_EDGES * 4);
    float* ew     = (float*)alloc((size_t)N_EDGES * 4);
    int*   counts = (int*)alloc((size_t)N_NODES * 4);
    float* dinv   = (float*)alloc((size_t)N_NODES * 4);
    int*   rowptr = (int*)alloc((size_t)(N_NODES + 1) * 4);
    int*   cursor = (int*)alloc((size_t)N_NODES * 4);
    int*   bsum   = (int*)alloc(512);
    int*   boff   = (int*)alloc(512);
    float* stats  = (float*)alloc(2 * HID * 4);
    float* scsh   = (float*)alloc(2 * HID * 4);
    int*   assign = (int*)alloc((size_t)M_LAB * 4);
    float* ccount = (float*)alloc(256);
    float* cfsum  = (float*)alloc((size_t)C_CLUST * HID * 4);
    float* cf     = (float*)alloc((size_t)C_CLUST * HID * 4);
    float* lut1   = (float*)alloc((size_t)C_CLUST * 1600 * 4);
    float* lut2   = (float*)alloc((size_t)C_CLUST * 1600 * 4);
    unsigned short* W0h = (unsigned short*)alloc((size_t)HID * IN_CH * 2);
    unsigned short* W0l = (unsigned short*)alloc((size_t)HID * IN_CH * 2);
    unsigned short* W1h = (unsigned short*)alloc((size_t)HID * HID * 2);
    unsigned short* W1l = (unsigned short*)alloc((size_t)HID * HID * 2);
    unsigned short* W2h = (unsigned short*)alloc((size_t)HID * HID * 2);
    unsigned short* W2l = (unsigned short*)alloc((size_t)HID * HID * 2);
    unsigned short* Fth = (unsigned short*)alloc((size_t)1600 * HID * 2);
    unsigned short* Ftl = (unsigned short*)alloc((size_t)1600 * HID * 2);
    unsigned short* Fbh = (unsigned short*)alloc((size_t)1600 * HID * 2);
    unsigned short* Fbl = (unsigned short*)alloc((size_t)1600 * HID * 2);
    unsigned short* xb  = (unsigned short*)alloc((size_t)N_NODES * IN_CH * 2);
    unsigned short* H2b = (unsigned short*)H2;  // alias: H2 fp32 dead after layer 0
    (void)ws_size; (void)in_sizes; (void)n_in; (void)out_size;

    const int* src = ei;
    const int* dst = ei + N_EDGES;

    // weight transpose + split; x -> bf16
    k_wsplit<<<dim3(4, 2), 256, 0, stream>>>(W0, HID, IN_CH, HID, W0h, W0l);
    k_wsplit<<<dim3(4, 4), 256, 0, stream>>>(W1, HID, HID, HID, W1h, W1l);
    k_wsplit<<<dim3(4, 4), 256, 0, stream>>>(W2, HID, HID, HID, W2h, W2l);
    k_wsplit<<<dim3(25, 4), 256, 0, stream>>>(fcW, 1600, HID, 1600, Fth, Ftl);
    k_wsplit<<<dim3(25, 4), 256, 0, stream>>>(fcW + (size_t)HID * 1600, 1600, HID, 1600, Fbh, Fbl);
    k_tobf16<<<(N_NODES * IN_CH / 8 + 255) / 256, 256, 0, stream>>>(x, xb, N_NODES * IN_CH / 8);

    // graph preprocessing -> CSR
    hipMemsetAsync(counts, 0, (size_t)N_NODES * 4, stream);
    k_count<<<(N_EDGES + 255) / 256, 256, 0, stream>>>(dst, counts);
    k_dinv<<<(N_NODES + 255) / 256, 256, 0, stream>>>(counts, dinv);
    k_scan1<<<98, 256, 0, stream>>>(counts, rowptr, bsum);
    k_scan2<<<1, 64, 0, stream>>>(bsum, boff, 98);
    k_scan3<<<98, 256, 0, stream>>>(rowptr, boff, cursor);
    k_scatter<<<(N_EDGES + 255) / 256, 256, 0, stream>>>(src, dst, dinv, cursor, col, ew);

    dim3 gg((N_NODES + GBM - 1) / GBM, HID / GBN);

    // ---- layer 0: agg(x_bf16) -> H2 fp32; H2 @ W0 + b0 -> H1 ----
    k_aggb<IN_CH><<<N_NODES / 16, 256, 0, stream>>>(xb, rowptr, col, ew, dinv,
                                                    nullptr, H2);
    k_mgemm<<<gg, 256, 0, stream>>>(H2, IN_CH, W0h, W0l, H1, nullptr, HID,
                                    N_NODES, HID, IN_CH,
                                    nullptr, nullptr, nullptr, b0, nullptr);
    hipMemsetAsync(stats, 0, 2 * HID * 4, stream);
    k_bnstats<<<512, 256, 0, stream>>>(H1, stats);
    k_bnfin<<<1, 256, 0, stream>>>(stats, g0, be0, scsh);

    // ---- layers 1, 2: GEMM (BN+ReLU fused, bf16 out) -> agg(bf16) -> H1 ----
    const unsigned short* Whs[2] = {W1h, W2h};
    const unsigned short* Wls[2] = {W1l, W2l};
    const float* bs[2] = {b1, b2};
    const float* gs[2] = {g1, g2};
    const float* bes[2] = {be1, be2};
    for (int l = 0; l < 2; l++) {
        k_mgemm<<<gg, 256, 0, stream>>>(H1, HID, Whs[l], Wls[l], nullptr, H2b, HID,
                                        N_NODES, HID, HID,
                                        nullptr, nullptr, nullptr, nullptr, scsh);
        k_aggb<HID><<<N_NODES / 8, 256, 0, stream>>>(H2b, rowptr, col, ew, dinv,
                                                     bs[l], H1);
        hipMemsetAsync(stats, 0, 2 * HID * 4, stream);
        k_bnstats<<<512, 256, 0, stream>>>(H1, stats);
        k_bnfin<<<1, 256, 0, stream>>>(stats, gs[l], bes[l], scsh);
    }

    // ---- cluster pooling (BN+ReLU of layer 2 fused into consumers) ----
    hipMemsetAsync(ccount, 0, 256, stream);
    hipMemsetAsync(cfsum, 0, (size_t)C_CLUST * HID * 4, stream);
    k_assign<<<(M_LAB + 255) / 256, 256, 0, stream>>>(cid, assign, ccount);
    k_csum<<<(M_LAB + 511) / 512, 256, 0, stream>>>(H1, cidx, assign, cfsum, scsh);
    k_cfin<<<C_CLUST, HID, 0, stream>>>(cfsum, ccount, cf);
    k_lut<<<dim3(7, C_CLUST), 256, 0, stream>>>(cf, fcW, fcb, lut1, lut2);

    // ---- final FC ----
    dim3 gf((M_LAB + GBM - 1) / GBM, (1600 + GBN - 1) / GBN);
    k_mgemm<<<gf, 256, 0, stream>>>(H1, HID, Fth, Ftl, out, nullptr, 1600,
                                    M_LAB, 1600, HID,
                                    cidx, assign, lut1, nullptr, scsh);
    k_mgemm<<<gf, 256, 0, stream>>>(H1, HID, Fbh, Fbl, out + (size_t)M_LAB * 1600,
                                    nullptr, 1600, M_LAB, 1600, HID,
                                    cidx, assign, lut2, nullptr, scsh);
}